// Round 4
// baseline (108.952 us; speedup 1.0000x reference)
//
#include <hip/hip_runtime.h>
#include <math.h>

// Problem constants (B=8, N=M=4096, D=2)
#define NPTS 4096
#define G    64      // grid is G x G = 4096 cells, row-major (j*G+i)

// One block per (side, query-tile): 16 sides x 16 tiles = 256 blocks, 256 thr.
// side s in 0..7 : queries = x[b],      stream = target[b]   (d_x_to_t)
// side s in 8..15: queries = target[b], stream = x[b]        (d_t_to_x)
// Each block redundantly builds its side's grid in LDS (counting sort), then
// answers 256 queries by exact expanding-ring search over LDS.
__global__ __launch_bounds__(256) void chamfer_grid(
    const float* __restrict__ x, const float* __restrict__ tgt,
    float* __restrict__ partials)
{
    __shared__ float2 spts[NPTS];      // 32 KB sorted stream points
    __shared__ int    sstart[NPTS + 4];// 16 KB cell start offsets (+end sentinel)
    __shared__ int    scnt[NPTS];      // 16 KB counts -> scatter cursors
    __shared__ float  misc[32];        // bbox wave partials
    __shared__ int    wtot[4];         // wave scan totals

    const int bid  = blockIdx.x;
    const int side = bid >> 4;
    const int tile = bid & 15;
    const int b    = side & 7;
    const int t    = threadIdx.x;
    const int lane = t & 63, w = t >> 6;

    const float* sarr = (side < 8) ? tgt : x;   // stream (binned) points
    const float* qarr = (side < 8) ? x   : tgt; // query points

    // ---- load 16 stream points per thread (interleaved, coalesced) ----
    const float4* p4 = (const float4*)(sarr + b * (NPTS * 2));
    float4 pk[8];
    #pragma unroll
    for (int k = 0; k < 8; ++k) pk[k] = p4[k * 256 + t];

    // ---- exact bbox of stream points (required for sound pruning) ----
    float mnx = INFINITY, mxx = -INFINITY, mny = INFINITY, mxy = -INFINITY;
    #pragma unroll
    for (int k = 0; k < 8; ++k) {
        mnx = fminf(mnx, fminf(pk[k].x, pk[k].z));
        mxx = fmaxf(mxx, fmaxf(pk[k].x, pk[k].z));
        mny = fminf(mny, fminf(pk[k].y, pk[k].w));
        mxy = fmaxf(mxy, fmaxf(pk[k].y, pk[k].w));
    }
    for (int off = 32; off; off >>= 1) {
        mnx = fminf(mnx, __shfl_down(mnx, off));
        mxx = fmaxf(mxx, __shfl_down(mxx, off));
        mny = fminf(mny, __shfl_down(mny, off));
        mxy = fmaxf(mxy, __shfl_down(mxy, off));
    }
    if (lane == 0) { misc[w] = mnx; misc[8+w] = mxx; misc[16+w] = mny; misc[24+w] = mxy; }
    // zero counters while the bbox lands
    #pragma unroll
    for (int k = 0; k < 16; ++k) scnt[t + 256 * k] = 0;
    __syncthreads();

    const float x0 = fminf(fminf(misc[0],  misc[1]),  fminf(misc[2],  misc[3]));
    const float x1 = fmaxf(fmaxf(misc[8],  misc[9]),  fmaxf(misc[10], misc[11]));
    const float y0 = fminf(fminf(misc[16], misc[17]), fminf(misc[18], misc[19]));
    const float y1 = fmaxf(fmaxf(misc[24], misc[25]), fmaxf(misc[26], misc[27]));
    const float invx = (float)G / (x1 - x0), invy = (float)G / (y1 - y0);
    const float cwx  = (x1 - x0) * (1.0f / G), cwy = (y1 - y0) * (1.0f / G);

    // ---- cell ids + LDS histogram ----
    int cell[16];
    #pragma unroll
    for (int k = 0; k < 8; ++k) {
        int ci0 = (int)((pk[k].x - x0) * invx); ci0 = ci0 > G-1 ? G-1 : ci0;
        int cj0 = (int)((pk[k].y - y0) * invy); cj0 = cj0 > G-1 ? G-1 : cj0;
        int ci1 = (int)((pk[k].z - x0) * invx); ci1 = ci1 > G-1 ? G-1 : ci1;
        int cj1 = (int)((pk[k].w - y0) * invy); cj1 = cj1 > G-1 ? G-1 : cj1;
        cell[2*k]   = cj0 * G + ci0;
        cell[2*k+1] = cj1 * G + ci1;
        atomicAdd(&scnt[cell[2*k]],   1);
        atomicAdd(&scnt[cell[2*k+1]], 1);
    }
    __syncthreads();

    // ---- exclusive scan of 4096 counts (16 per thread) ----
    const int base = t * 16;
    int loc[16]; int run = 0;
    #pragma unroll
    for (int k = 0; k < 16; ++k) { loc[k] = run; run += scnt[base + k]; }
    int v = run;
    for (int off = 1; off < 64; off <<= 1) {
        int u = __shfl_up(v, off);
        if (lane >= off) v += u;
    }
    if (lane == 63) wtot[w] = v;
    __syncthreads();
    int wbase = 0;
    #pragma unroll
    for (int ww = 0; ww < 4; ++ww) wbase += (ww < w) ? wtot[ww] : 0;
    const int tbase = wbase + v - run;   // exclusive prefix of this thread's run
    #pragma unroll
    for (int k = 0; k < 16; ++k) {
        const int st = tbase + loc[k];
        sstart[base + k] = st;
        scnt[base + k]   = st;           // scatter cursor
    }
    if (t == 0) sstart[NPTS] = NPTS;
    __syncthreads();

    // ---- scatter into sorted order (order within cell irrelevant: fmin) ----
    #pragma unroll
    for (int k = 0; k < 16; ++k) {
        const int pos = atomicAdd(&scnt[cell[k]], 1);
        spts[pos] = (k & 1) ? make_float2(pk[k>>1].z, pk[k>>1].w)
                            : make_float2(pk[k>>1].x, pk[k>>1].y);
    }
    __syncthreads();

    // ---- query: exact NN via expanding Chebyshev rings ----
    const float2 q = ((const float2*)(qarr + b * (NPTS * 2)))[tile * 256 + t];
    const float gx = (q.x - x0) * invx, gy = (q.y - y0) * invy;
    int ci = (int)floorf(gx); ci = ci < 0 ? 0 : (ci > G-1 ? G-1 : ci);
    int cj = (int)floorf(gy); cj = cj < 0 ? 0 : (cj > G-1 ? G-1 : cj);
    const float fx = gx - (float)ci, fy = gy - (float)cj;

    float best = INFINITY;
    {   // center cell
        const int cc = cj * G + ci;
        const int s = sstart[cc], e = sstart[cc + 1];
        for (int k = s; k < e; ++k) {
            const float2 p = spts[k];
            const float dx = q.x - p.x, dy = q.y - p.y;
            best = fminf(best, fmaf(dx, dx, dy * dy));
        }
    }
    for (int r = 1; r < G; ++r) {
        // exact lower bound on distance to any ring-r cell (monotone in r)
        const float bnd = fminf(fminf((r - 1 + fx) * cwx, (r - fx) * cwx),
                                fminf((r - 1 + fy) * cwy, (r - fy) * cwy));
        if (bnd > 0.f && bnd * bnd >= best) break;
        const int ilo = ci - r < 0 ? 0 : ci - r;
        const int ihi = ci + r > G-1 ? G-1 : ci + r;
        const int jt = cj - r, jb = cj + r;
        if (jt >= 0) {   // top row: contiguous cell range -> one point range
            const int s = sstart[jt * G + ilo], e = sstart[jt * G + ihi + 1];
            for (int k = s; k < e; ++k) {
                const float2 p = spts[k];
                const float dx = q.x - p.x, dy = q.y - p.y;
                best = fminf(best, fmaf(dx, dx, dy * dy));
            }
        }
        if (jb <= G-1) { // bottom row
            const int s = sstart[jb * G + ilo], e = sstart[jb * G + ihi + 1];
            for (int k = s; k < e; ++k) {
                const float2 p = spts[k];
                const float dx = q.x - p.x, dy = q.y - p.y;
                best = fminf(best, fmaf(dx, dx, dy * dy));
            }
        }
        const int jlo = cj - r + 1 < 0 ? 0 : cj - r + 1;
        const int jhi = cj + r - 1 > G-1 ? G-1 : cj + r - 1;
        if (ci - r >= 0) {   // left column (excl. corners)
            const int col = ci - r;
            for (int j = jlo; j <= jhi; ++j) {
                const int c = j * G + col;
                const int s = sstart[c], e = sstart[c + 1];
                for (int k = s; k < e; ++k) {
                    const float2 p = spts[k];
                    const float dx = q.x - p.x, dy = q.y - p.y;
                    best = fminf(best, fmaf(dx, dx, dy * dy));
                }
            }
        }
        if (ci + r <= G-1) { // right column
            const int col = ci + r;
            for (int j = jlo; j <= jhi; ++j) {
                const int c = j * G + col;
                const int s = sstart[c], e = sstart[c + 1];
                for (int k = s; k < e; ++k) {
                    const float2 p = spts[k];
                    const float dx = q.x - p.x, dy = q.y - p.y;
                    best = fminf(best, fmaf(dx, dx, dy * dy));
                }
            }
        }
    }
    const float dval = sqrtf(best);

    // ---- block sum -> partials ----
    __syncthreads();                  // everyone done reading spts
    float* red = (float*)spts;
    red[t] = dval;
    __syncthreads();
    if (t < 64) {
        float v2 = red[t] + red[t + 64] + red[t + 128] + red[t + 192];
        v2 += __shfl_down(v2, 32);
        v2 += __shfl_down(v2, 16);
        v2 += __shfl_down(v2, 8);
        v2 += __shfl_down(v2, 4);
        v2 += __shfl_down(v2, 2);
        v2 += __shfl_down(v2, 1);
        if (t == 0) partials[bid] = v2;
    }
}

__global__ __launch_bounds__(256) void chamfer_final(
    const float* __restrict__ partials, float* __restrict__ out)
{
    __shared__ float red[256];
    const int tid = threadIdx.x;
    red[tid] = partials[tid];
    __syncthreads();
    if (tid < 64) {
        float v = red[tid] + red[tid + 64] + red[tid + 128] + red[tid + 192];
        v += __shfl_down(v, 32);
        v += __shfl_down(v, 16);
        v += __shfl_down(v, 8);
        v += __shfl_down(v, 4);
        v += __shfl_down(v, 2);
        v += __shfl_down(v, 1);
        // mean(d_t_to_x) + mean(d_x_to_t): both halves divide by B*4096 = 32768
        if (tid == 0) out[0] = v * (1.0f / 32768.0f);
    }
}

extern "C" void kernel_launch(void* const* d_in, const int* in_sizes, int n_in,
                              void* d_out, int out_size, void* d_ws, size_t ws_size,
                              hipStream_t stream) {
    const float* x   = (const float*)d_in[0];
    const float* tgt = (const float*)d_in[1];
    float* partials  = (float*)d_ws;   // 256 floats
    float* out       = (float*)d_out;  // 1 float

    chamfer_grid<<<dim3(256), dim3(256), 0, stream>>>(x, tgt, partials);
    chamfer_final<<<dim3(1), dim3(256), 0, stream>>>(partials, out);
}

// Round 5
// 74.210 us; speedup vs baseline: 1.4682x; 1.4682x over previous
//
#include <hip/hip_runtime.h>
#include <math.h>

// Problem constants (B=8, N=M=4096, D=2)
#define NPTS 4096
#define G    128
#define NC   (G * G)      // 16384 cells
#define HALF (NC / 2)     // 8192 packed u16 pairs

// ws layout (floats), per side (16 sides = 2 dirs x 8 batches):
#define OFF_BBOX 0                    // 4 floats: x0,x1,y0,y1 (stream bbox)
#define OFF_SPR  16                   // sorted stream pts, row-major cells (8192 f)
#define OFF_SPC  8208                 // sorted stream pts, col-major cells (8192 f)
#define OFF_Q    16400                // morton-sorted queries (8192 f)
#define OFF_SSR  24592                // row-major cell starts, u16[NC+1] packed in u32[8193] (+pad)
#define OFF_SSC  32800                // col-major cell starts
#define SIDE_STRIDE 41984
#define OFF_PART (16 * SIDE_STRIDE)   // 256 block partials

__device__ __forceinline__ unsigned int mort(unsigned int a, unsigned int b) {
    a = (a | (a << 8)) & 0x00FF00FFu; a = (a | (a << 4)) & 0x0F0F0F0Fu;
    a = (a | (a << 2)) & 0x33333333u; a = (a | (a << 1)) & 0x55555555u;
    b = (b | (b << 8)) & 0x00FF00FFu; b = (b | (b << 4)) & 0x0F0F0F0Fu;
    b = (b | (b << 2)) & 0x33333333u; b = (b | (b << 1)) & 0x55555555u;
    return a | (b << 1);   // 14 bits < NC
}

// Kernel A: 48 blocks = 16 sides x 3 roles.
// role 0: counting-sort stream pts by row-major cell, emit starts + bbox
// role 1: counting-sort stream pts by col-major cell, emit starts
// role 2: counting-sort query pts by morton cell (spatial coherence only)
__global__ __launch_bounds__(256) void chamfer_build(
    const float* __restrict__ x, const float* __restrict__ tgt,
    float* __restrict__ ws)
{
    __shared__ unsigned int counts[NC];   // 64 KB
    __shared__ float2 spts[NPTS];         // 32 KB
    __shared__ float misc[32];
    __shared__ int wtot[4];

    const int bid  = blockIdx.x;
    const int side = bid / 3;
    const int role = bid - 3 * side;
    const int b    = side & 7;
    const int t    = threadIdx.x;
    const int lane = t & 63, w = t >> 6;
    float* wsS = ws + (size_t)side * SIDE_STRIDE;

    const float* sarr = (side < 8) ? tgt : x;   // stream (binned) points
    const float* qarr = (side < 8) ? x   : tgt; // query points
    const float* pts  = (role == 2) ? qarr : sarr;

    #pragma unroll
    for (int k = 0; k < NC / 256; ++k) counts[k * 256 + t] = 0u;

    // ---- load 16 points (coalesced) ----
    const float4* p4 = (const float4*)(pts + b * (NPTS * 2));
    float4 pk[8];
    #pragma unroll
    for (int k = 0; k < 8; ++k) pk[k] = p4[k * 256 + t];

    // ---- exact bbox of loaded points ----
    float mnx = INFINITY, mxx = -INFINITY, mny = INFINITY, mxy = -INFINITY;
    #pragma unroll
    for (int k = 0; k < 8; ++k) {
        mnx = fminf(mnx, fminf(pk[k].x, pk[k].z));
        mxx = fmaxf(mxx, fmaxf(pk[k].x, pk[k].z));
        mny = fminf(mny, fminf(pk[k].y, pk[k].w));
        mxy = fmaxf(mxy, fmaxf(pk[k].y, pk[k].w));
    }
    for (int off = 32; off; off >>= 1) {
        mnx = fminf(mnx, __shfl_down(mnx, off));
        mxx = fmaxf(mxx, __shfl_down(mxx, off));
        mny = fminf(mny, __shfl_down(mny, off));
        mxy = fmaxf(mxy, __shfl_down(mxy, off));
    }
    if (lane == 0) { misc[w] = mnx; misc[8+w] = mxx; misc[16+w] = mny; misc[24+w] = mxy; }
    __syncthreads();
    const float x0 = fminf(fminf(misc[0],  misc[1]),  fminf(misc[2],  misc[3]));
    const float x1 = fmaxf(fmaxf(misc[8],  misc[9]),  fmaxf(misc[10], misc[11]));
    const float y0 = fminf(fminf(misc[16], misc[17]), fminf(misc[18], misc[19]));
    const float y1 = fmaxf(fmaxf(misc[24], misc[25]), fmaxf(misc[26], misc[27]));
    const float invx = (float)G / (x1 - x0), invy = (float)G / (y1 - y0);

    // ---- cell keys + histogram ----
    int cell[16];
    #pragma unroll
    for (int k = 0; k < 8; ++k) {
        int ci0 = (int)((pk[k].x - x0) * invx); ci0 = ci0 < 0 ? 0 : (ci0 > G-1 ? G-1 : ci0);
        int cj0 = (int)((pk[k].y - y0) * invy); cj0 = cj0 < 0 ? 0 : (cj0 > G-1 ? G-1 : cj0);
        int ci1 = (int)((pk[k].z - x0) * invx); ci1 = ci1 < 0 ? 0 : (ci1 > G-1 ? G-1 : ci1);
        int cj1 = (int)((pk[k].w - y0) * invy); cj1 = cj1 < 0 ? 0 : (cj1 > G-1 ? G-1 : cj1);
        cell[2*k]   = (role == 0) ? cj0 * G + ci0 : (role == 1) ? ci0 * G + cj0 : (int)mort(ci0, cj0);
        cell[2*k+1] = (role == 0) ? cj1 * G + ci1 : (role == 1) ? ci1 * G + cj1 : (int)mort(ci1, cj1);
        atomicAdd(&counts[cell[2*k]],   1u);
        atomicAdd(&counts[cell[2*k+1]], 1u);
    }
    __syncthreads();

    // ---- exclusive scan of NC counts (64/thread, two-pass) ----
    const int base = t * (NC / 256);
    unsigned int run = 0;
    for (int k = 0; k < NC / 256; ++k) run += counts[base + k];
    int v = (int)run;
    for (int off = 1; off < 64; off <<= 1) {
        int u = __shfl_up(v, off);
        if (lane >= off) v += u;
    }
    if (lane == 63) wtot[w] = v;
    __syncthreads();
    int wbase = 0;
    #pragma unroll
    for (int ww = 0; ww < 4; ++ww) wbase += (ww < w) ? wtot[ww] : 0;
    unsigned int c = (unsigned int)(wbase + v - (int)run);
    for (int k = 0; k < NC / 256; ++k) {
        const unsigned int cnt = counts[base + k];
        counts[base + k] = c;   // counts[] now holds starts
        c += cnt;
    }
    __syncthreads();

    // ---- emit starts (u16 packed) before scatter mutates them ----
    if (role < 2) {
        unsigned int* gss = (unsigned int*)(wsS + ((role == 0) ? OFF_SSR : OFF_SSC));
        for (int i = t; i < HALF; i += 256)
            gss[i] = counts[2*i] | (counts[2*i + 1] << 16);
        if (t == 0) gss[HALF] = (unsigned)NPTS | ((unsigned)NPTS << 16);  // sentinel
    }
    if (role == 0 && t == 0) {
        wsS[OFF_BBOX + 0] = x0; wsS[OFF_BBOX + 1] = x1;
        wsS[OFF_BBOX + 2] = y0; wsS[OFF_BBOX + 3] = y1;
    }
    __syncthreads();

    // ---- scatter (order within cell irrelevant: fmin/sum downstream) ----
    #pragma unroll
    for (int k = 0; k < 16; ++k) {
        const unsigned int pos = atomicAdd(&counts[cell[k]], 1u);
        spts[pos] = (k & 1) ? make_float2(pk[k >> 1].z, pk[k >> 1].w)
                            : make_float2(pk[k >> 1].x, pk[k >> 1].y);
    }
    __syncthreads();

    // ---- coalesced copy out ----
    float4* gsp = (float4*)(wsS + ((role == 0) ? OFF_SPR : (role == 1) ? OFF_SPC : OFF_Q));
    const float4* sp4 = (const float4*)spts;
    #pragma unroll
    for (int k = 0; k < 8; ++k) gsp[k * 256 + t] = sp4[k * 256 + t];
}

__device__ __forceinline__ float scan_pts(const float2* __restrict__ p, int s, int e,
                                          float qx, float qy, float best)
{
    for (int k = s; k < e; ++k) {
        const float2 pt = p[k];
        const float dx = qx - pt.x, dy = qy - pt.y;
        best = fminf(best, fmaf(dx, dx, dy * dy));
    }
    return best;
}

// Kernel B: 256 blocks x 256 thr; 1 morton-sorted query per thread.
__global__ __launch_bounds__(256) void chamfer_query(
    const float* __restrict__ ws, float* __restrict__ partials)
{
    __shared__ float4 sR4[NPTS / 2];        // 32 KB row-major sorted pts
    __shared__ float4 sC4[NPTS / 2];        // 32 KB col-major sorted pts
    __shared__ uint4  ssR4[HALF / 4 + 2];   // 32.8 KB row starts (u16 view)
    __shared__ uint4  ssC4[HALF / 4 + 2];   // 32.8 KB col starts

    const int bid  = blockIdx.x;
    const int side = bid >> 4, tile = bid & 15;
    const int t    = threadIdx.x;
    const float* wsS = ws + (size_t)side * SIDE_STRIDE;

    // ---- stage side data into LDS ----
    const float4* gR = (const float4*)(wsS + OFF_SPR);
    const float4* gC = (const float4*)(wsS + OFF_SPC);
    #pragma unroll
    for (int k = 0; k < 8; ++k) {
        sR4[k * 256 + t] = gR[k * 256 + t];
        sC4[k * 256 + t] = gC[k * 256 + t];
    }
    const uint4* gssR = (const uint4*)(wsS + OFF_SSR);
    const uint4* gssC = (const uint4*)(wsS + OFF_SSC);
    #pragma unroll
    for (int k = 0; k < 9; ++k) {
        const int i = k * 256 + t;
        if (i < HALF / 4 + 1) { ssR4[i] = gssR[i]; ssC4[i] = gssC[i]; }
    }
    const float x0 = wsS[OFF_BBOX + 0], x1 = wsS[OFF_BBOX + 1];
    const float y0 = wsS[OFF_BBOX + 2], y1 = wsS[OFF_BBOX + 3];
    const float2 q = ((const float2*)(wsS + OFF_Q))[tile * 256 + t];
    const float invx = (float)G / (x1 - x0), invy = (float)G / (y1 - y0);
    const float cwx = (x1 - x0) * (1.0f / G), cwy = (y1 - y0) * (1.0f / G);
    __syncthreads();

    const float2* pR = (const float2*)sR4;
    const float2* pC = (const float2*)sC4;
    const unsigned short* hR = (const unsigned short*)ssR4;
    const unsigned short* hC = (const unsigned short*)ssC4;

    // ---- exact NN: expanding Chebyshev rings, all 4 edges as ranges ----
    const float gxf = (q.x - x0) * invx, gyf = (q.y - y0) * invy;
    int ci = (int)floorf(gxf); ci = ci < 0 ? 0 : (ci > G-1 ? G-1 : ci);
    int cj = (int)floorf(gyf); cj = cj < 0 ? 0 : (cj > G-1 ? G-1 : cj);
    const float fx = gxf - (float)ci, fy = gyf - (float)cj;

    float best = INFINITY;
    {
        const int cc = cj * G + ci;
        best = scan_pts(pR, hR[cc], hR[cc + 1], q.x, q.y, best);
    }
    for (int r = 1; r < G; ++r) {
        // exact lower bound on distance to any unvisited ring-r cell
        const float bnd = fminf(fminf((r - 1 + fx) * cwx, (r - fx) * cwx),
                                fminf((r - 1 + fy) * cwy, (r - fy) * cwy));
        if (bnd > 0.f && bnd * bnd >= best) break;
        const int ilo = ci - r < 0 ? 0 : ci - r;
        const int ihi = ci + r > G-1 ? G-1 : ci + r;
        if (cj - r >= 0) {      // top row: one contiguous range
            const int ro = (cj - r) * G;
            best = scan_pts(pR, hR[ro + ilo], hR[ro + ihi + 1], q.x, q.y, best);
        }
        if (cj + r <= G-1) {    // bottom row
            const int ro = (cj + r) * G;
            best = scan_pts(pR, hR[ro + ilo], hR[ro + ihi + 1], q.x, q.y, best);
        }
        const int jlo = cj - r + 1 < 0 ? 0 : cj - r + 1;
        const int jhi = cj + r - 1 > G-1 ? G-1 : cj + r - 1;
        if (jlo <= jhi) {
            if (ci - r >= 0) {  // left column: contiguous in col-major copy
                const int co = (ci - r) * G;
                best = scan_pts(pC, hC[co + jlo], hC[co + jhi + 1], q.x, q.y, best);
            }
            if (ci + r <= G-1) { // right column
                const int co = (ci + r) * G;
                best = scan_pts(pC, hC[co + jlo], hC[co + jhi + 1], q.x, q.y, best);
            }
        }
    }
    const float dval = sqrtf(fmaxf(best, 0.f));

    // ---- block sum -> partials ----
    __syncthreads();
    float* red = (float*)sR4;
    red[t] = dval;
    __syncthreads();
    if (t < 64) {
        float v = red[t] + red[t + 64] + red[t + 128] + red[t + 192];
        v += __shfl_down(v, 32);
        v += __shfl_down(v, 16);
        v += __shfl_down(v, 8);
        v += __shfl_down(v, 4);
        v += __shfl_down(v, 2);
        v += __shfl_down(v, 1);
        if (t == 0) partials[bid] = v;
    }
}

__global__ __launch_bounds__(256) void chamfer_final(
    const float* __restrict__ partials, float* __restrict__ out)
{
    __shared__ float red[256];
    const int tid = threadIdx.x;
    red[tid] = partials[tid];
    __syncthreads();
    if (tid < 64) {
        float v = red[tid] + red[tid + 64] + red[tid + 128] + red[tid + 192];
        v += __shfl_down(v, 32);
        v += __shfl_down(v, 16);
        v += __shfl_down(v, 8);
        v += __shfl_down(v, 4);
        v += __shfl_down(v, 2);
        v += __shfl_down(v, 1);
        // mean(d_t_to_x) + mean(d_x_to_t): both divide by B*4096 = 32768
        if (tid == 0) out[0] = v * (1.0f / 32768.0f);
    }
}

extern "C" void kernel_launch(void* const* d_in, const int* in_sizes, int n_in,
                              void* d_out, int out_size, void* d_ws, size_t ws_size,
                              hipStream_t stream) {
    const float* x   = (const float*)d_in[0];
    const float* tgt = (const float*)d_in[1];
    float* ws        = (float*)d_ws;       // needs ~2.7 MB
    float* partials  = ws + OFF_PART;      // 256 floats
    float* out       = (float*)d_out;      // 1 float

    chamfer_build<<<dim3(48),  dim3(256), 0, stream>>>(x, tgt, ws);
    chamfer_query<<<dim3(256), dim3(256), 0, stream>>>(ws, partials);
    chamfer_final<<<dim3(1),   dim3(256), 0, stream>>>(partials, out);
}

// Round 6
// 39.327 us; speedup vs baseline: 2.7704x; 1.8870x over previous
//
#include <hip/hip_runtime.h>
#include <math.h>

// Problem constants (B=8, N=M=4096, D=2)
#define NPTS 4096
#define G    64
#define NC   (G * G)          // 4096 cells
#define HALF (NC / 2)         // 2048 packed u16-pair words

// ws layout (floats) per side; sides 0..7 = batch b, queries=x, stream=target
//                              sides 8..15 = batch b, queries=target, stream=x
#define OFF_SS 0              // u32[2049]: packed u16 cell starts (+sentinel)
#define OFF_SP 2056           // row-cell-sorted stream points float2[4096]
#define OFF_Q  10248          // morton-sorted query points float2[4096]
#define OFF_BB 18440          // x0,x1,y0,y1  (UNION bbox of batch: same both sides)
#define SIDE_STRIDE 18448
#define OFF_PART (16 * SIDE_STRIDE)

__device__ __forceinline__ unsigned int mort(unsigned int a, unsigned int b) {
    a = (a | (a << 8)) & 0x00FF00FFu; a = (a | (a << 4)) & 0x0F0F0F0Fu;
    a = (a | (a << 2)) & 0x33333333u; a = (a | (a << 1)) & 0x55555555u;
    b = (b | (b << 8)) & 0x00FF00FFu; b = (b | (b << 4)) & 0x0F0F0F0Fu;
    b = (b | (b << 2)) & 0x33333333u; b = (b | (b << 1)) & 0x55555555u;
    return a | (b << 1);   // 12 bits for 6-bit inputs
}

// Kernel A: 32 blocks = 8 batches x 4 roles.
// role 0: stream sort (tgt, row-cell)  -> side b      (+ bbox, starts)
// role 1: stream sort (x,   row-cell)  -> side b+8    (+ bbox, starts)
// role 2: query sort  (x,   morton)    -> side b
// role 3: query sort  (tgt, morton)    -> side b+8
// All roles compute the batch UNION bbox with identical code/order -> identical.
__global__ __launch_bounds__(256) void chamfer_build(
    const float* __restrict__ x, const float* __restrict__ tgt,
    float* __restrict__ ws)
{
    __shared__ unsigned int counts[NC];   // 16 KB
    __shared__ float2 spts[NPTS];         // 32 KB
    __shared__ float misc[32];
    __shared__ int wtot[4];

    const int bid   = blockIdx.x;
    const int batch = bid >> 2, role = bid & 3;
    const int t = threadIdx.x, lane = t & 63, w = t >> 6;
    const int side = (role == 0 || role == 2) ? batch : batch + 8;
    float* wsS = ws + (size_t)side * SIDE_STRIDE;

    const float4* xb = (const float4*)(x   + batch * (NPTS * 2));
    const float4* tb = (const float4*)(tgt + batch * (NPTS * 2));
    const bool keep_x = (role == 1 || role == 2);

    #pragma unroll
    for (int k = 0; k < NC / 256; ++k) counts[k * 256 + t] = 0u;

    // ---- union bbox of BOTH arrays (fixed order => identical in all roles) ----
    float mnx = INFINITY, mxx = -INFINITY, mny = INFINITY, mxy = -INFINITY;
    float4 pk[8];
    #pragma unroll
    for (int k = 0; k < 8; ++k) {
        const float4 a = xb[k * 256 + t];
        mnx = fminf(mnx, fminf(a.x, a.z)); mxx = fmaxf(mxx, fmaxf(a.x, a.z));
        mny = fminf(mny, fminf(a.y, a.w)); mxy = fmaxf(mxy, fmaxf(a.y, a.w));
        if (keep_x) pk[k] = a;
    }
    #pragma unroll
    for (int k = 0; k < 8; ++k) {
        const float4 a = tb[k * 256 + t];
        mnx = fminf(mnx, fminf(a.x, a.z)); mxx = fmaxf(mxx, fmaxf(a.x, a.z));
        mny = fminf(mny, fminf(a.y, a.w)); mxy = fmaxf(mxy, fmaxf(a.y, a.w));
        if (!keep_x) pk[k] = a;
    }
    for (int off = 32; off; off >>= 1) {
        mnx = fminf(mnx, __shfl_down(mnx, off));
        mxx = fmaxf(mxx, __shfl_down(mxx, off));
        mny = fminf(mny, __shfl_down(mny, off));
        mxy = fmaxf(mxy, __shfl_down(mxy, off));
    }
    if (lane == 0) { misc[w] = mnx; misc[8+w] = mxx; misc[16+w] = mny; misc[24+w] = mxy; }
    __syncthreads();
    const float x0 = fminf(fminf(misc[0],  misc[1]),  fminf(misc[2],  misc[3]));
    const float x1 = fmaxf(fmaxf(misc[8],  misc[9]),  fmaxf(misc[10], misc[11]));
    const float y0 = fminf(fminf(misc[16], misc[17]), fminf(misc[18], misc[19]));
    const float y1 = fmaxf(fmaxf(misc[24], misc[25]), fmaxf(misc[26], misc[27]));
    const float invx = (float)G / (x1 - x0), invy = (float)G / (y1 - y0);

    // ---- keys + histogram ----
    int cell[16];
    #pragma unroll
    for (int k = 0; k < 8; ++k) {
        int ci0 = (int)((pk[k].x - x0) * invx); ci0 = ci0 < 0 ? 0 : (ci0 > G-1 ? G-1 : ci0);
        int cj0 = (int)((pk[k].y - y0) * invy); cj0 = cj0 < 0 ? 0 : (cj0 > G-1 ? G-1 : cj0);
        int ci1 = (int)((pk[k].z - x0) * invx); ci1 = ci1 < 0 ? 0 : (ci1 > G-1 ? G-1 : ci1);
        int cj1 = (int)((pk[k].w - y0) * invy); cj1 = cj1 < 0 ? 0 : (cj1 > G-1 ? G-1 : cj1);
        cell[2*k]   = (role < 2) ? cj0 * G + ci0 : (int)mort((unsigned)ci0, (unsigned)cj0);
        cell[2*k+1] = (role < 2) ? cj1 * G + ci1 : (int)mort((unsigned)ci1, (unsigned)cj1);
        atomicAdd(&counts[cell[2*k]],   1u);
        atomicAdd(&counts[cell[2*k+1]], 1u);
    }
    __syncthreads();

    // ---- exclusive scan of NC=4096 counts (16/thread) ----
    const int base = t * 16;
    unsigned int loc[16]; unsigned int run = 0;
    #pragma unroll
    for (int k = 0; k < 16; ++k) { loc[k] = run; run += counts[base + k]; }
    int v = (int)run;
    for (int off = 1; off < 64; off <<= 1) {
        int u = __shfl_up(v, off);
        if (lane >= off) v += u;
    }
    if (lane == 63) wtot[w] = v;
    __syncthreads();
    int wbase = 0;
    #pragma unroll
    for (int ww = 0; ww < 4; ++ww) wbase += (ww < w) ? wtot[ww] : 0;
    const unsigned int tb0 = (unsigned int)(wbase + v - (int)run);
    #pragma unroll
    for (int k = 0; k < 16; ++k) counts[base + k] = tb0 + loc[k];  // starts
    __syncthreads();

    // ---- emit starts (packed u16) + bbox, then scatter ----
    if (role < 2) {
        unsigned int* gss = (unsigned int*)(wsS + OFF_SS);
        for (int i = t; i < HALF; i += 256)
            gss[i] = counts[2*i] | (counts[2*i + 1] << 16);
        if (t == 0) {
            gss[HALF] = (unsigned)NPTS | ((unsigned)NPTS << 16);  // sentinel
            wsS[OFF_BB + 0] = x0; wsS[OFF_BB + 1] = x1;
            wsS[OFF_BB + 2] = y0; wsS[OFF_BB + 3] = y1;
        }
    }
    __syncthreads();
    #pragma unroll
    for (int k = 0; k < 16; ++k) {
        const unsigned int pos = atomicAdd(&counts[cell[k]], 1u);
        spts[pos] = (k & 1) ? make_float2(pk[k >> 1].z, pk[k >> 1].w)
                            : make_float2(pk[k >> 1].x, pk[k >> 1].y);
    }
    __syncthreads();
    float4* gsp = (float4*)(wsS + ((role < 2) ? OFF_SP : OFF_Q));
    const float4* sp = (const float4*)spts;
    #pragma unroll
    for (int k = 0; k < 8; ++k) gsp[k * 256 + t] = sp[k * 256 + t];
}

__device__ __forceinline__ float scan_pts(const float2* __restrict__ p, int s, int e,
                                          float qx, float qy, float best)
{
    for (int k = s; k < e; ++k) {
        const float2 pt = p[k];
        const float dx = qx - pt.x, dy = qy - pt.y;
        best = fminf(best, fmaf(dx, dx, dy * dy));
    }
    return best;
}

// Kernel B: 256 blocks x 256 thr; wave w of block tile handles morton group w*16+tile
// (strided assignment spreads slow spatial regions across blocks).
__global__ __launch_bounds__(256) void chamfer_query(
    const float* __restrict__ ws, float* __restrict__ partials)
{
    __shared__ float4 sp4[NPTS / 2];       // 32 KB sorted stream points
    __shared__ unsigned int ss[HALF + 4];  // 8.2 KB packed u16 starts

    const int bid  = blockIdx.x;
    const int side = bid >> 4, tile = bid & 15;
    const int t    = threadIdx.x;
    const float* wsS = ws + (size_t)side * SIDE_STRIDE;

    const float4* gp = (const float4*)(wsS + OFF_SP);
    #pragma unroll
    for (int k = 0; k < 8; ++k) sp4[k * 256 + t] = gp[k * 256 + t];
    const unsigned int* gss = (const unsigned int*)(wsS + OFF_SS);
    #pragma unroll
    for (int k = 0; k < 9; ++k) {
        const int i = k * 256 + t;
        if (i <= HALF) ss[i] = gss[i];
    }
    const float x0 = wsS[OFF_BB + 0], x1 = wsS[OFF_BB + 1];
    const float y0 = wsS[OFF_BB + 2], y1 = wsS[OFF_BB + 3];
    const int g = (t >> 6) * 16 + tile;   // morton group for this wave
    const float2 q = ((const float2*)(wsS + OFF_Q))[g * 64 + (t & 63)];
    const float invx = (float)G / (x1 - x0), invy = (float)G / (y1 - y0);
    const float cwx = (x1 - x0) * (1.0f / G), cwy = (y1 - y0) * (1.0f / G);
    __syncthreads();

    const float2* pR = (const float2*)sp4;
    const unsigned short* hS = (const unsigned short*)ss;

    // queries are INSIDE the union bbox -> fx,fy in [0,1], bound always valid
    const float gxf = (q.x - x0) * invx, gyf = (q.y - y0) * invy;
    int ci = (int)gxf; ci = ci < 0 ? 0 : (ci > G-1 ? G-1 : ci);
    int cj = (int)gyf; cj = cj < 0 ? 0 : (cj > G-1 ? G-1 : cj);
    const float fx = gxf - (float)ci, fy = gyf - (float)cj;

    // ---- phase 1: full 3x3 neighborhood (3 contiguous row ranges) ----
    float best = INFINITY;
    {
        const int ilo = ci - 1 < 0 ? 0 : ci - 1;
        const int ihi = ci + 1 > G-1 ? G-1 : ci + 1;
        const int jt  = cj - 1 < 0 ? 0 : cj - 1;
        const int jb  = cj + 1 > G-1 ? G-1 : cj + 1;
        for (int j = jt; j <= jb; ++j) {
            const int ro = j * G;
            best = scan_pts(pR, hS[ro + ilo], hS[ro + ihi + 1], q.x, q.y, best);
        }
    }

    // ---- phase 2: expanding rings with edge-existence-masked lower bound ----
    for (int r = 2; r <= G; ++r) {
        const bool hasL = (ci - r >= 0), hasR = (ci + r <= G-1);
        const bool hasT = (cj - r >= 0), hasB = (cj + r <= G-1);
        float bnd = INFINITY;
        if (hasL) bnd = fminf(bnd, ((float)(r-1) + fx) * cwx);
        if (hasR) bnd = fminf(bnd, ((float)r - fx) * cwx);
        if (hasT) bnd = fminf(bnd, ((float)(r-1) + fy) * cwy);
        if (hasB) bnd = fminf(bnd, ((float)r - fy) * cwy);
        if (bnd * bnd >= best) break;   // includes bnd==INF (ring exhausted)

        const int ilo = ci - r < 0 ? 0 : ci - r;
        const int ihi = ci + r > G-1 ? G-1 : ci + r;
        if (hasT) {
            const int ro = (cj - r) * G;
            best = scan_pts(pR, hS[ro + ilo], hS[ro + ihi + 1], q.x, q.y, best);
        }
        if (hasB) {
            const int ro = (cj + r) * G;
            best = scan_pts(pR, hS[ro + ilo], hS[ro + ihi + 1], q.x, q.y, best);
        }
        const int jlo = cj - r + 1 < 0 ? 0 : cj - r + 1;
        const int jhi = cj + r - 1 > G-1 ? G-1 : cj + r - 1;
        if (hasL) {
            const int col = ci - r;
            for (int j = jlo; j <= jhi; ++j) {
                const int c = j * G + col;
                best = scan_pts(pR, hS[c], hS[c + 1], q.x, q.y, best);
            }
        }
        if (hasR) {
            const int col = ci + r;
            for (int j = jlo; j <= jhi; ++j) {
                const int c = j * G + col;
                best = scan_pts(pR, hS[c], hS[c + 1], q.x, q.y, best);
            }
        }
    }
    const float dval = sqrtf(fmaxf(best, 0.f));

    // ---- block sum -> partials ----
    __syncthreads();
    float* red = (float*)sp4;
    red[t] = dval;
    __syncthreads();
    if (t < 64) {
        float v = red[t] + red[t + 64] + red[t + 128] + red[t + 192];
        v += __shfl_down(v, 32);
        v += __shfl_down(v, 16);
        v += __shfl_down(v, 8);
        v += __shfl_down(v, 4);
        v += __shfl_down(v, 2);
        v += __shfl_down(v, 1);
        if (t == 0) partials[bid] = v;
    }
}

__global__ __launch_bounds__(256) void chamfer_final(
    const float* __restrict__ partials, float* __restrict__ out)
{
    __shared__ float red[256];
    const int tid = threadIdx.x;
    red[tid] = partials[tid];
    __syncthreads();
    if (tid < 64) {
        float v = red[tid] + red[tid + 64] + red[tid + 128] + red[tid + 192];
        v += __shfl_down(v, 32);
        v += __shfl_down(v, 16);
        v += __shfl_down(v, 8);
        v += __shfl_down(v, 4);
        v += __shfl_down(v, 2);
        v += __shfl_down(v, 1);
        // mean(d_t_to_x) + mean(d_x_to_t): both divide by B*4096 = 32768
        if (tid == 0) out[0] = v * (1.0f / 32768.0f);
    }
}

extern "C" void kernel_launch(void* const* d_in, const int* in_sizes, int n_in,
                              void* d_out, int out_size, void* d_ws, size_t ws_size,
                              hipStream_t stream) {
    const float* x   = (const float*)d_in[0];
    const float* tgt = (const float*)d_in[1];
    float* ws        = (float*)d_ws;       // ~1.2 MB used
    float* partials  = ws + OFF_PART;      // 256 floats
    float* out       = (float*)d_out;      // 1 float

    chamfer_build<<<dim3(32),  dim3(256), 0, stream>>>(x, tgt, ws);
    chamfer_query<<<dim3(256), dim3(256), 0, stream>>>(ws, partials);
    chamfer_final<<<dim3(1),   dim3(256), 0, stream>>>(partials, out);
}